// Round 19
// baseline (139.715 us; speedup 1.0000x reference)
//
#include <hip/hip_runtime.h>
#include <hip/hip_bf16.h>

#define DEV static __device__ __forceinline__

typedef __attribute__((ext_vector_type(8))) short bf16x8;
typedef __attribute__((ext_vector_type(4))) short bf16x4;
typedef __attribute__((ext_vector_type(4))) float f32x4;

#define MFMA16(a, b, c) __builtin_amdgcn_mfma_f32_16x16x32_bf16((a), (b), (c), 0, 0, 0)

// 16x16x16 bf16 MFMA: C/D layout of a previous 16x16 MFMA == this op's B-frag
// layout, so S^T (post-softmax, in registers) feeds PV^T with no data movement.
DEV f32x4 pv_mfma(bf16x4 a, bf16x4 b, f32x4 c) {
#if __has_builtin(__builtin_amdgcn_mfma_f32_16x16x16_bf16)
  return __builtin_amdgcn_mfma_f32_16x16x16_bf16(a, b, c, 0, 0, 0);
#elif __has_builtin(__builtin_amdgcn_mfma_f32_16x16x16bf16_1k)
  return __builtin_amdgcn_mfma_f32_16x16x16bf16_1k(a, b, c, 0, 0, 0);
#else
  f32x4 d;
  asm volatile("v_mfma_f32_16x16x16_bf16 %0, %1, %2, %3"
               : "=v"(d) : "v"(a), "v"(b), "v"(c));
  return d;
#endif
}

// packed f32 pair -> bf16x4 via 2x v_cvt_pk_bf16_f32 (proven R9/R13/R15)
DEV bf16x4 pk4(float e0, float e1, float e2, float e3) {
  unsigned lo, hi;
  asm("v_cvt_pk_bf16_f32 %0, %1, %2" : "=v"(lo) : "v"(e0), "v"(e1));
  asm("v_cvt_pk_bf16_f32 %0, %1, %2" : "=v"(hi) : "v"(e2), "v"(e3));
  union { unsigned u[2]; bf16x4 v; } r;
  r.u[0] = lo; r.u[1] = hi;
  return r.v;
}

#define B_ 2
#define T_ 2048
#define D_ 1024
#define H_ 16
#define HD_ 64
#define LOG2E 1.4426950408889634f

DEV short f2bf(float f) {
  union { float f; unsigned u; } w; w.f = f;
  unsigned u = w.u + 0x7fffu + ((w.u >> 16) & 1u);
  return (short)(u >> 16);
}

// global -> LDS direct staging, 16B per lane: lane i writes LDS at l + i*16.
DEV void gld16(const void* g, void* l) {
  __builtin_amdgcn_global_load_lds(
      (const __attribute__((address_space(1))) void*)g,
      (__attribute__((address_space(3))) void*)l, 16, 0, 0);
}

// ---------------- convert x / w_attn / w_proj fp32 -> bf16 + rope table
#define XN 4194304   // 4096*1024
#define WAN 3145728  // 3072*1024
__global__ void cvt_k(const float* __restrict__ x, const float* __restrict__ wa,
                      const float* __restrict__ wp, short* __restrict__ xb,
                      short* __restrict__ wab, short* __restrict__ wpb,
                      float2* __restrict__ tab) {
  size_t gi = ((size_t)blockIdx.x * 256 + threadIdx.x) * 8;
  const float* src; short* dst;
  if (gi < XN) { src = x + gi; dst = xb + gi; }
  else if (gi < XN + WAN) { src = wa + (gi - XN); dst = wab + (gi - XN); }
  else { src = wp + (gi - XN - WAN); dst = wpb + (gi - XN - WAN); }
  float4 a = *(const float4*)src;
  float4 b = *(const float4*)(src + 4);
  bf16x8 o;
  o[0] = f2bf(a.x); o[1] = f2bf(a.y); o[2] = f2bf(a.z); o[3] = f2bf(a.w);
  o[4] = f2bf(b.x); o[5] = f2bf(b.y); o[6] = f2bf(b.z); o[7] = f2bf(b.w);
  *(bf16x8*)dst = o;
  if (blockIdx.x < 256) {
    int i = blockIdx.x * 256 + threadIdx.x;  // < 65536 = T_*32
    int t = i >> 5, d = i & 31;
    float theta = powf(10000.0f, -(float)(2 * d) / 64.0f);
    float ang = (float)t * theta;
    tab[i] = make_float2(cosf(ang), sinf(ang));
  }
}

// ---------------- m97-style bf16 GEMM core (proven R6): 128x128, BK=64, 4 waves.
#define GEMM_CORE(Aptr, Bptr, KDIM)                                              \
  __shared__ short aT[128 * 64];                                                 \
  __shared__ short bT[128 * 64];                                                 \
  const int tid = threadIdx.x;                                                   \
  const int lane = tid & 63, w = tid >> 6;                                       \
  const int l15 = lane & 15, lg = lane >> 4;                                     \
  const int wr = w >> 1, wc = w & 1;                                             \
  const int mBase = blockIdx.y * 128, nBase = blockIdx.x * 128;                  \
  const int lrow = lane >> 3;                                                    \
  const int gch = (lane & 7) ^ lrow;                                             \
  const short* Asrc = (Aptr) + (size_t)(mBase + w * 32 + lrow) * (KDIM) + gch * 8;\
  const short* Bsrc = (Bptr) + (size_t)(nBase + w * 32 + lrow) * (KDIM) + gch * 8;\
  short* aDst = aT + w * 2048;                                                   \
  short* bDst = bT + w * 2048;                                                   \
  f32x4 acc[4][4];                                                               \
  _Pragma("unroll") for (int i = 0; i < 4; ++i)                                  \
  _Pragma("unroll") for (int j = 0; j < 4; ++j)                                  \
      acc[i][j] = (f32x4){0.f, 0.f, 0.f, 0.f};                                   \
  const int nk = (KDIM) / 64;                                                    \
  for (int kt = 0; kt < nk; ++kt) {                                              \
    if (kt) __syncthreads();                                                     \
    _Pragma("unroll") for (int p = 0; p < 4; ++p) {                              \
      gld16(Asrc + kt * 64 + p * 8 * (KDIM), aDst + p * 512);                    \
      gld16(Bsrc + kt * 64 + p * 8 * (KDIM), bDst + p * 512);                    \
    }                                                                            \
    __syncthreads(); /* compiler drains vmcnt(0) before barrier */               \
    bf16x8 af[4][2], bfv[4][2];                                                  \
    _Pragma("unroll") for (int i = 0; i < 4; ++i)                                \
    _Pragma("unroll") for (int s = 0; s < 2; ++s) {                              \
      const int ra = wr * 64 + i * 16 + l15;                                     \
      const int rb = wc * 64 + i * 16 + l15;                                     \
      af[i][s] = *(const bf16x8*)&aT[ra * 64 + (((4 * s + lg) ^ (ra & 7)) * 8)]; \
      bfv[i][s] = *(const bf16x8*)&bT[rb * 64 + (((4 * s + lg) ^ (rb & 7)) * 8)];\
    }                                                                            \
    _Pragma("unroll") for (int mi = 0; mi < 4; ++mi)                             \
    _Pragma("unroll") for (int ni = 0; ni < 4; ++ni)                             \
    _Pragma("unroll") for (int s = 0; s < 2; ++s)                                \
        acc[mi][ni] = MFMA16(af[mi][s], bfv[ni][s], acc[mi][ni]);                \
  }

// ---------------- K1: qkv = x @ w_attn^T (bf16), fused RoPE epilogue.
__global__ void gemm_qkv_k(const short* __restrict__ Xb, const short* __restrict__ Wb,
                           short* __restrict__ Q, short* __restrict__ Ko,
                           short* __restrict__ Vt, const float2* __restrict__ tab) {
  GEMM_CORE(Xb, Wb, 1024)

  const int sec = nBase >> 10;
#pragma unroll
  for (int mi = 0; mi < 4; ++mi) {
    const int m0 = mBase + wr * 64 + mi * 16 + lg * 4;
#pragma unroll
    for (int ni = 0; ni < 4; ++ni) {
      const int n = nBase + wc * 64 + ni * 16 + l15;
      const int hd = n & 63;
      const int h = (n >> 6) & 15;
      if (sec < 2) {
        short* dst = (sec == 0) ? Q : Ko;
        const float qscale = (sec == 0) ? (0.125f * LOG2E) : 1.0f;
#pragma unroll
        for (int r = 0; r < 4; ++r) {
          int m = m0 + r; int b = m >> 11; int t = m & 2047;
          float v = acc[mi][ni][r];
          float pv = __shfl_xor(v, 1);  // rope pair partner (adjacent lane)
          float2 cs = tab[t * 32 + (hd >> 1)];
          float o = (lane & 1) ? (v * cs.x + pv * cs.y) : (v * cs.x - pv * cs.y);
          o *= qscale;
          dst[(((size_t)b * H_ + h) * T_ + t) * HD_ + hd] = f2bf(o);
        }
      } else {
        int b = m0 >> 11; int t0 = m0 & 2047;
        short4 s4;
        s4.x = f2bf(acc[mi][ni][0]); s4.y = f2bf(acc[mi][ni][1]);
        s4.z = f2bf(acc[mi][ni][2]); s4.w = f2bf(acc[mi][ni][3]);
        *(short4*)&Vt[(((size_t)b * H_ + h) * HD_ + hd) * T_ + t0] = s4;
      }
    }
  }
}

// ---------------- K2: flash attention. QBLK=64, grid 1024 (4 blocks/CU), 512
// threads / 8 waves in TWO groups: per barrier interval the block stages a PAIR
// of k-tiles; group 0 (waves 0-3) computes the even tile, group 1 the odd tile.
// Serial chain per block halves (30 -> ~15 intervals) and blocks/CU doubles.
// Inner chain = R13/R15-proven swapped chain (no pLds). Epilogue: group 1
// deposits unnormalized O^T + row-sums in LDS; group 0 adds, normalizes once,
// transpose-stores Y.
#define HB 4608  // 64*72 shorts per tile buffer
__global__ __launch_bounds__(512, 4) void attn_k(const short* __restrict__ Qg,
                                                 const short* __restrict__ Kg,
                                                 const short* __restrict__ Vg,
                                                 short* __restrict__ Y) {
  __shared__ short kB[2 * HB];   // K buffers for (even, odd) tile of the pair
  __shared__ short vB[2 * HB];   // V^T buffers
  const int tid = threadIdx.x;
  const int lane = tid & 63, w = tid >> 6;   // w 0..7
  const int g = w >> 2, wl = w & 3;          // group, wave-in-group
  const int l15 = lane & 15, lg = lane >> 4;
  const int bid = blockIdx.x;
  const int wg = ((bid & 7) << 7) | (bid >> 3);  // XCD swizzle: 128 blocks/XCD
  const int qt = wg & 31, bh = wg >> 5;
  const int b = bh >> 4, h = bh & 15;
  const int q0 = qt * 64;
  const short* Qh = Qg + (size_t)bh * T_ * HD_;
  const short* Kh = Kg + (size_t)bh * T_ * HD_;
  const short* Vh = Vg + (size_t)bh * HD_ * T_;

  // Q as B-fragment: C/B col l15 -> q-row q0 + wl*16 + l15 (both groups same q)
  const int qrow = q0 + wl * 16 + l15;
  bf16x8 qb[2];
  qb[0] = *(const bf16x8*)&Qh[(size_t)qrow * HD_ + lg * 8];
  qb[1] = *(const bf16x8*)&Qh[(size_t)qrow * HD_ + 32 + lg * 8];

  f32x4 ot[4];
#pragma unroll
  for (int i = 0; i < 4; ++i) ot[i] = (f32x4){0.f, 0.f, 0.f, 0.f};
  float lsum = 0.f;

  // staging: 512 threads cover one 64x64 tile per bf16x8; pair = kreg/vreg[2]
  const int sRow = tid >> 3, sC = (tid & 7) * 8;
  bf16x8 kreg[2], vreg[2];
  auto issueLoad = [&](int pi) {
    const int k0p = pi * 128;
#pragma unroll
    for (int p = 0; p < 2; ++p) {
      kreg[p] = *(const bf16x8*)&Kh[(size_t)(k0p + p * 64 + sRow) * HD_ + sC];
      vreg[p] = *(const bf16x8*)&Vh[(size_t)sRow * T_ + k0p + p * 64 + sC];
    }
  };
  // tile fully banned for q-range [q0, q0+63]: k0 in [q0-65, q0+65]
  auto bannedTile = [&](int kt) { const int k0 = kt * 64; return k0 >= q0 - 65 && k0 <= q0 + 65; };
  auto pairBanned = [&](int pi) { return bannedTile(2 * pi) && bannedTile(2 * pi + 1); };

  const int NP = T_ / 128;  // 16 pairs
  int pi = 0;
  while (pi < NP && pairBanned(pi)) ++pi;
  issueLoad(pi);

  while (pi < NP) {
    int pn = pi + 1;
    while (pn < NP && pairBanned(pn)) ++pn;

    __syncthreads();  // previous interval's LDS readers done
#pragma unroll
    for (int p = 0; p < 2; ++p) {
      *(bf16x8*)&kB[p * HB + sRow * 72 + sC] = kreg[p];
      *(bf16x8*)&vB[p * HB + sRow * 72 + sC] = vreg[p];
    }
    if (pn < NP) issueLoad(pn);  // T14: in flight across barrier, under compute
    asm volatile("s_waitcnt lgkmcnt(0)" ::: "memory");
    __builtin_amdgcn_s_barrier();

    const int ktg = 2 * pi + g;       // this group's tile
    const int k0 = ktg * 64;
    if (!bannedTile(ktg)) {           // wave-uniform (g fixed per wave)
      // conservative 64-row clean bound (R13-proven form)
      const bool clean = (q0 >= 16) && (k0 >= 16) &&
                         ((k0 + 63 < q0 - 128) || (k0 > q0 + 63 + 128));
      const short* kb_ = kB + g * HB;
      const short* vb_ = vB + g * HB;

      // QK^T swapped: S^T[k][q]
      f32x4 s[4];
#pragma unroll
      for (int i = 0; i < 4; ++i) s[i] = (f32x4){0.f, 0.f, 0.f, 0.f};
      __builtin_amdgcn_s_setprio(1);
#pragma unroll
      for (int nf = 0; nf < 4; ++nf)
#pragma unroll
        for (int ks = 0; ks < 2; ++ks) {
          bf16x8 ka = *(const bf16x8*)&kb_[(nf * 16 + l15) * 72 + ks * 32 + lg * 8];
          s[nf] = MFMA16(ka, qb[ks], s[nf]);
        }
      __builtin_amdgcn_s_setprio(0);

      // mask + exp2 + pack; j = k0 + nf*16 + lg*4 + r is lane-local, q = qrow
      bf16x4 pf[4];
#pragma unroll
      for (int nf = 0; nf < 4; ++nf) {
        float e[4];
#pragma unroll
        for (int r = 0; r < 4; ++r) {
          if (!clean) {
            const int j = k0 + nf * 16 + lg * 4 + r;
            const bool keep = (qrow >= 16) && (j >= 16) &&
                              ((j < qrow - 128) || (j > qrow + 128));
            if (!keep) s[nf][r] = -__builtin_inff();
          }
          e[r] = __builtin_amdgcn_exp2f(s[nf][r]);
          lsum += e[r];
        }
        pf[nf] = pk4(e[0], e[1], e[2], e[3]);
      }

      // PV^T: O^T[d][q] += V^T-frag x P^T-frag; va loaded JIT
      __builtin_amdgcn_s_setprio(1);
#pragma unroll
      for (int kk = 0; kk < 4; ++kk) {
        bf16x4 va[4];
#pragma unroll
        for (int dt = 0; dt < 4; ++dt)
          va[dt] = *(const bf16x4*)&vb_[(dt * 16 + l15) * 72 + kk * 16 + lg * 4];
#pragma unroll
        for (int dt = 0; dt < 4; ++dt)
          ot[dt] = pv_mfma(va[dt], pf[kk], ot[dt]);
      }
      __builtin_amdgcn_s_setprio(0);
    }
    pi = pn;
  }

  // row-sum reduce (both groups): q at l15; partials across lanes l15+16k
  float l = lsum;
  l += __shfl_xor(l, 16);
  l += __shfl_xor(l, 32);

  // cross-group combine: g1 deposits O^T + l into LDS; g0 adds + normalizes.
  __syncthreads();  // last interval's buffer readers done before reuse
  float* ex = (float*)kB;                      // 4 waves x 1024 fp32 = 16 KB
  float* exl = (float*)((char*)kB + 16384);    // 64 fp32
  if (g == 1) {
#pragma unroll
    for (int dt = 0; dt < 4; ++dt)
#pragma unroll
      for (int j = 0; j < 4; ++j)
        ex[wl * 1024 + (dt * 16 + lg * 4 + j) * 16 + l15] = ot[dt][j];
    if (lane < 16) exl[wl * 16 + l15] = l;
  }
  __syncthreads();
  if (g == 0) {
#pragma unroll
    for (int dt = 0; dt < 4; ++dt)
#pragma unroll
      for (int j = 0; j < 4; ++j)
        ot[dt][j] += ex[wl * 1024 + (dt * 16 + lg * 4 + j) * 16 + l15];
    l += exl[wl * 16 + l15];
    const float rl = 1.0f / fmaxf(l, 1e-20f);

    // coalesced Y store via wave-private LDS transpose (reuse vB)
    short* tl = (short*)vB + wl * (16 * 72);
#pragma unroll
    for (int dt = 0; dt < 4; ++dt) {
      short4 s4;
      s4.x = f2bf(ot[dt][0] * rl);
      s4.y = f2bf(ot[dt][1] * rl);
      s4.z = f2bf(ot[dt][2] * rl);
      s4.w = f2bf(ot[dt][3] * rl);
      *(short4*)&tl[l15 * 72 + dt * 16 + lg * 4] = s4;  // LDS[q][d]
    }
    const int rr = lane >> 3, cc = (lane & 7) * 8;
#pragma unroll
    for (int hf = 0; hf < 2; ++hf) {
      const int row = hf * 8 + rr;
      bf16x8 v = *(const bf16x8*)&tl[row * 72 + cc];
      const int t = q0 + wl * 16 + row;
      *(bf16x8*)&Y[((size_t)(b * T_ + t)) * D_ + h * HD_ + cc] = v;
    }
  }
}

// ---------------- K3: out = y @ w_proj^T (bf16 x bf16 -> fp32)
__global__ void gemm_proj_k(const short* __restrict__ Yg, const short* __restrict__ Wb,
                            float* __restrict__ Out) {
  GEMM_CORE(Yg, Wb, 1024)

#pragma unroll
  for (int mi = 0; mi < 4; ++mi)
#pragma unroll
    for (int ni = 0; ni < 4; ++ni)
#pragma unroll
      for (int r = 0; r < 4; ++r)
        Out[(size_t)(mBase + wr * 64 + mi * 16 + lg * 4 + r) * 1024 +
            nBase + wc * 64 + ni * 16 + l15] = acc[mi][ni][r];
}

extern "C" void kernel_launch(void* const* d_in, const int* in_sizes, int n_in,
                              void* d_out, int out_size, void* d_ws, size_t ws_size,
                              hipStream_t stream) {
  const float* x = (const float*)d_in[0];
  const float* w_attn = (const float*)d_in[1];
  const float* w_proj = (const float*)d_in[2];
  float* out = (float*)d_out;
  char* ws = (char*)d_ws;
  char* outc = (char*)d_out;
  // ws: Q 8MB | K 8MB | Vt 8MB | Y 8MB | Wpb 2MB   (~34MB)
  short* Q   = (short*)(ws);
  short* K   = (short*)(ws + (size_t)8388608);
  short* Vt  = (short*)(ws + (size_t)16777216);
  short* Y   = (short*)(ws + (size_t)25165824);
  short* Wpb = (short*)(ws + (size_t)33554432);
  // d_out doubles as scratch for data dead before gemm_proj writes it:
  short* Xb   = (short*)(outc);
  short* Wab  = (short*)(outc + (size_t)8388608);
  float2* tab = (float2*)(outc + (size_t)14680064);

  cvt_k<<<dim3(4096), dim3(256), 0, stream>>>(x, w_attn, w_proj, Xb, Wab, Wpb, tab);
  gemm_qkv_k<<<dim3(24, 32), dim3(256), 0, stream>>>(Xb, Wab, Q, K, Vt, tab);
  attn_k<<<dim3(B_ * H_ * (T_ / 64)), dim3(512), 0, stream>>>(Q, K, Vt, Y);
  gemm_proj_k<<<dim3(8, 32), dim3(256), 0, stream>>>(Y, Wpb, out);
}

// Round 20
// 129.475 us; speedup vs baseline: 1.0791x; 1.0791x over previous
//
#include <hip/hip_runtime.h>
#include <hip/hip_bf16.h>

#define DEV static __device__ __forceinline__

typedef __attribute__((ext_vector_type(8))) short bf16x8;
typedef __attribute__((ext_vector_type(4))) float f32x4;

#define MFMA16(a, b, c) __builtin_amdgcn_mfma_f32_16x16x32_bf16((a), (b), (c), 0, 0, 0)

#define B_ 2
#define T_ 2048
#define D_ 1024
#define H_ 16
#define HD_ 64
#define LOG2E 1.4426950408889634f

DEV short f2bf(float f) {
  union { float f; unsigned u; } w; w.f = f;
  unsigned u = w.u + 0x7fffu + ((w.u >> 16) & 1u);
  return (short)(u >> 16);
}

// global -> LDS direct staging, 16B per lane: lane i writes LDS at l + i*16.
DEV void gld16(const void* g, void* l) {
  __builtin_amdgcn_global_load_lds(
      (const __attribute__((address_space(1))) void*)g,
      (__attribute__((address_space(3))) void*)l, 16, 0, 0);
}

// ---------------- convert x / w_attn / w_proj fp32 -> bf16 + rope table
// (rope-table generation folded in: blocks 0..255 each fill 256 entries,
// saving one serialized launch; consumers run two launches later)
#define XN 4194304   // 4096*1024
#define WAN 3145728  // 3072*1024
__global__ void cvt_k(const float* __restrict__ x, const float* __restrict__ wa,
                      const float* __restrict__ wp, short* __restrict__ xb,
                      short* __restrict__ wab, short* __restrict__ wpb,
                      float2* __restrict__ tab) {
  size_t gi = ((size_t)blockIdx.x * 256 + threadIdx.x) * 8;
  const float* src; short* dst;
  if (gi < XN) { src = x + gi; dst = xb + gi; }
  else if (gi < XN + WAN) { src = wa + (gi - XN); dst = wab + (gi - XN); }
  else { src = wp + (gi - XN - WAN); dst = wpb + (gi - XN - WAN); }
  float4 a = *(const float4*)src;
  float4 b = *(const float4*)(src + 4);
  bf16x8 o;
  o[0] = f2bf(a.x); o[1] = f2bf(a.y); o[2] = f2bf(a.z); o[3] = f2bf(a.w);
  o[4] = f2bf(b.x); o[5] = f2bf(b.y); o[6] = f2bf(b.z); o[7] = f2bf(b.w);
  *(bf16x8*)dst = o;
  if (blockIdx.x < 256) {
    int i = blockIdx.x * 256 + threadIdx.x;  // < 65536 = T_*32
    int t = i >> 5, d = i & 31;
    float theta = powf(10000.0f, -(float)(2 * d) / 64.0f);
    float ang = (float)t * theta;
    tab[i] = make_float2(cosf(ang), sinf(ang));
  }
}

// ---------------- m97-style bf16 GEMM core (proven R6): 128x128, BK=64, 4 waves.
#define GEMM_CORE(Aptr, Bptr, KDIM)                                              \
  __shared__ short aT[128 * 64];                                                 \
  __shared__ short bT[128 * 64];                                                 \
  const int tid = threadIdx.x;                                                   \
  const int lane = tid & 63, w = tid >> 6;                                       \
  const int l15 = lane & 15, lg = lane >> 4;                                     \
  const int wr = w >> 1, wc = w & 1;                                             \
  const int mBase = blockIdx.y * 128, nBase = blockIdx.x * 128;                  \
  const int lrow = lane >> 3;                                                    \
  const int gch = (lane & 7) ^ lrow;                                             \
  const short* Asrc = (Aptr) + (size_t)(mBase + w * 32 + lrow) * (KDIM) + gch * 8;\
  const short* Bsrc = (Bptr) + (size_t)(nBase + w * 32 + lrow) * (KDIM) + gch * 8;\
  short* aDst = aT + w * 2048;                                                   \
  short* bDst = bT + w * 2048;                                                   \
  f32x4 acc[4][4];                                                               \
  _Pragma("unroll") for (int i = 0; i < 4; ++i)                                  \
  _Pragma("unroll") for (int j = 0; j < 4; ++j)                                  \
      acc[i][j] = (f32x4){0.f, 0.f, 0.f, 0.f};                                   \
  const int nk = (KDIM) / 64;                                                    \
  for (int kt = 0; kt < nk; ++kt) {                                              \
    if (kt) __syncthreads();                                                     \
    _Pragma("unroll") for (int p = 0; p < 4; ++p) {                              \
      gld16(Asrc + kt * 64 + p * 8 * (KDIM), aDst + p * 512);                    \
      gld16(Bsrc + kt * 64 + p * 8 * (KDIM), bDst + p * 512);                    \
    }                                                                            \
    __syncthreads(); /* compiler drains vmcnt(0) before barrier */               \
    bf16x8 af[4][2], bfv[4][2];                                                  \
    _Pragma("unroll") for (int i = 0; i < 4; ++i)                                \
    _Pragma("unroll") for (int s = 0; s < 2; ++s) {                              \
      const int ra = wr * 64 + i * 16 + l15;                                     \
      const int rb = wc * 64 + i * 16 + l15;                                     \
      af[i][s] = *(const bf16x8*)&aT[ra * 64 + (((4 * s + lg) ^ (ra & 7)) * 8)]; \
      bfv[i][s] = *(const bf16x8*)&bT[rb * 64 + (((4 * s + lg) ^ (rb & 7)) * 8)];\
    }                                                                            \
    _Pragma("unroll") for (int mi = 0; mi < 4; ++mi)                             \
    _Pragma("unroll") for (int ni = 0; ni < 4; ++ni)                             \
    _Pragma("unroll") for (int s = 0; s < 2; ++s)                                \
        acc[mi][ni] = MFMA16(af[mi][s], bfv[ni][s], acc[mi][ni]);                \
  }

// ---------------- K1: qkv = x @ w_attn^T (bf16), fused RoPE epilogue.
__global__ void gemm_qkv_k(const short* __restrict__ Xb, const short* __restrict__ Wb,
                           short* __restrict__ Q, short* __restrict__ Ko,
                           short* __restrict__ Vt, const float2* __restrict__ tab) {
  GEMM_CORE(Xb, Wb, 1024)

  const int sec = nBase >> 10;
#pragma unroll
  for (int mi = 0; mi < 4; ++mi) {
    const int m0 = mBase + wr * 64 + mi * 16 + lg * 4;
#pragma unroll
    for (int ni = 0; ni < 4; ++ni) {
      const int n = nBase + wc * 64 + ni * 16 + l15;
      const int hd = n & 63;
      const int h = (n >> 6) & 15;
      if (sec < 2) {
        short* dst = (sec == 0) ? Q : Ko;
        const float qscale = (sec == 0) ? (0.125f * LOG2E) : 1.0f;
#pragma unroll
        for (int r = 0; r < 4; ++r) {
          int m = m0 + r; int b = m >> 11; int t = m & 2047;
          float v = acc[mi][ni][r];
          float pv = __shfl_xor(v, 1);  // rope pair partner (adjacent lane)
          float2 cs = tab[t * 32 + (hd >> 1)];
          float o = (lane & 1) ? (v * cs.x + pv * cs.y) : (v * cs.x - pv * cs.y);
          o *= qscale;
          dst[(((size_t)b * H_ + h) * T_ + t) * HD_ + hd] = f2bf(o);
        }
      } else {
        int b = m0 >> 11; int t0 = m0 & 2047;
        short4 s4;
        s4.x = f2bf(acc[mi][ni][0]); s4.y = f2bf(acc[mi][ni][1]);
        s4.z = f2bf(acc[mi][ni][2]); s4.w = f2bf(acc[mi][ni][3]);
        *(short4*)&Vt[(((size_t)b * H_ + h) * HD_ + hd) * T_ + t0] = s4;
      }
    }
  }
}

// ---------------- K2: flash attention (R11/R18 exactly — session best:
// 76.6us, VGPR 48, WRITE 8.2MB). 512 threads / 8 waves: waves 0-3 own q-tile
// q0, waves 4-7 own q0+64, sharing one staged K/V tile. (512,4): 128-VGPR cap,
// no spill; occupancy LDS-bound.
#define QBLK 128
__global__ __launch_bounds__(512, 4) void attn_k(const short* __restrict__ Qg,
                                                 const short* __restrict__ Kg,
                                                 const short* __restrict__ Vg,
                                                 short* __restrict__ Y) {
  __shared__ short kLds[64 * 72];
  __shared__ short vLds[64 * 72];
  __shared__ short pLds[2 * 64 * 72];
  const int tid = threadIdx.x;
  const int lane = tid & 63, w = tid >> 6;   // w 0..7
  const int g = w >> 2, wl = w & 3;          // q-group, wave-in-group
  const int l15 = lane & 15, lg = lane >> 4;
  const int bid = blockIdx.x;
  const int wg = ((bid & 7) << 6) | (bid >> 3);  // XCD swizzle: 64 blocks/XCD
  const int qt = wg & 15, bh = wg >> 4;
  const int b = bh >> 4, h = bh & 15;
  const int q0 = qt * QBLK;
  const int qg = q0 + g * 64;                // this wave's 64-row q-tile
  const short* Qh = Qg + (size_t)bh * T_ * HD_;
  const short* Kh = Kg + (size_t)bh * T_ * HD_;
  const short* Vh = Vg + (size_t)bh * HD_ * T_;
  short* pl = pLds + g * 4608;

  bf16x8 qa[2];
  {
    const int qrow = qg + wl * 16 + l15;
    qa[0] = *(const bf16x8*)&Qh[(size_t)qrow * HD_ + lg * 8];
    qa[1] = *(const bf16x8*)&Qh[(size_t)qrow * HD_ + 32 + lg * 8];
  }
  f32x4 o[4];
#pragma unroll
  for (int i = 0; i < 4; ++i) o[i] = (f32x4){0.f, 0.f, 0.f, 0.f};
  float lsum[4] = {0.f, 0.f, 0.f, 0.f};

  // staging: 512 threads cover the 64x64 K tile and V^T tile in ONE bf16x8 each
  const int sRow = tid >> 3, sC = (tid & 7) * 8;
  bf16x8 kreg, vreg;
  auto issueLoad = [&](int kt) {
    const int k0 = kt * 64;
    kreg = *(const bf16x8*)&Kh[(size_t)(k0 + sRow) * HD_ + sC];
    vreg = *(const bf16x8*)&Vh[(size_t)sRow * T_ + k0 + sC];
  };
  // banned for BOTH q-tiles (block-uniform): k0 in [q0-1, q0+65]
  auto bothBanned = [&](int kt) { const int k0 = kt * 64; return k0 >= q0 - 1 && k0 <= q0 + 65; };

  const int NT = T_ / 64;
  int kt = 0;
  while (kt < NT && bothBanned(kt)) ++kt;
  issueLoad(kt);

  while (kt < NT) {
    int ktn = kt + 1;
    while (ktn < NT && bothBanned(ktn)) ++ktn;

    __syncthreads();
    *(bf16x8*)&kLds[sRow * 72 + sC] = kreg;
    *(bf16x8*)&vLds[sRow * 72 + sC] = vreg;
    if (ktn < NT) issueLoad(ktn);  // T14: flies under compute, across the barrier
    asm volatile("s_waitcnt lgkmcnt(0)" ::: "memory");
    __builtin_amdgcn_s_barrier();

    const int k0 = kt * 64;
    if (!(k0 >= qg - 65 && k0 <= qg + 65)) {  // wave-uniform compute skip
      const bool clean = (qg >= 16) && (k0 >= 16) &&
                         ((k0 + 63 < qg - 128) || (k0 > qg + 63 + 128));

      f32x4 s[4];
#pragma unroll
      for (int i = 0; i < 4; ++i) s[i] = (f32x4){0.f, 0.f, 0.f, 0.f};
#pragma unroll
      for (int nf = 0; nf < 4; ++nf)
#pragma unroll
        for (int ks = 0; ks < 2; ++ks) {
          bf16x8 kb = *(const bf16x8*)&kLds[(nf * 16 + l15) * 72 + ks * 32 + lg * 8];
          s[nf] = MFMA16(qa[ks], kb, s[nf]);
        }

      if (!clean) {
#pragma unroll
        for (int nf = 0; nf < 4; ++nf) {
          const int j = k0 + nf * 16 + l15;
#pragma unroll
          for (int r = 0; r < 4; ++r) {
            const int i = qg + wl * 16 + lg * 4 + r;
            const bool keep = (i >= 16) && (j >= 16) && ((j < i - 128) || (j > i + 128));
            if (!keep) s[nf][r] = -__builtin_inff();
          }
        }
      }

#pragma unroll
      for (int nf = 0; nf < 4; ++nf)
#pragma unroll
        for (int r = 0; r < 4; ++r) {
          float e = __builtin_amdgcn_exp2f(s[nf][r]);
          lsum[r] += e;
          pl[(wl * 16 + lg * 4 + r) * 72 + nf * 16 + l15] = f2bf(e);
        }
#pragma unroll
      for (int nf = 0; nf < 4; ++nf)
#pragma unroll
        for (int ks = 0; ks < 2; ++ks) {
          bf16x8 pa = *(const bf16x8*)&pl[(wl * 16 + l15) * 72 + ks * 32 + lg * 8];
          bf16x8 vb = *(const bf16x8*)&vLds[(nf * 16 + l15) * 72 + ks * 32 + lg * 8];
          o[nf] = MFMA16(pa, vb, o[nf]);
        }
    }
    kt = ktn;
  }

  float rl[4];
#pragma unroll
  for (int r = 0; r < 4; ++r) {
    float v = lsum[r];
    v += __shfl_xor(v, 1);
    v += __shfl_xor(v, 2);
    v += __shfl_xor(v, 4);
    v += __shfl_xor(v, 8);
    rl[r] = 1.0f / fmaxf(v, 1e-20f);
  }
#pragma unroll
  for (int nf = 0; nf < 4; ++nf)
#pragma unroll
    for (int r = 0; r < 4; ++r) {
      const int t = qg + wl * 16 + lg * 4 + r;
      Y[((size_t)(b * T_ + t)) * D_ + h * HD_ + nf * 16 + l15] = f2bf(o[nf][r] * rl[r]);
    }
}

// ---------------- K3: out = y @ w_proj^T (bf16 x bf16 -> fp32)
__global__ void gemm_proj_k(const short* __restrict__ Yg, const short* __restrict__ Wb,
                            float* __restrict__ Out) {
  GEMM_CORE(Yg, Wb, 1024)

#pragma unroll
  for (int mi = 0; mi < 4; ++mi)
#pragma unroll
    for (int ni = 0; ni < 4; ++ni)
#pragma unroll
      for (int r = 0; r < 4; ++r)
        Out[(size_t)(mBase + wr * 64 + mi * 16 + lg * 4 + r) * 1024 +
            nBase + wc * 64 + ni * 16 + l15] = acc[mi][ni][r];
}

extern "C" void kernel_launch(void* const* d_in, const int* in_sizes, int n_in,
                              void* d_out, int out_size, void* d_ws, size_t ws_size,
                              hipStream_t stream) {
  const float* x = (const float*)d_in[0];
  const float* w_attn = (const float*)d_in[1];
  const float* w_proj = (const float*)d_in[2];
  float* out = (float*)d_out;
  char* ws = (char*)d_ws;
  char* outc = (char*)d_out;
  // ws: Q 8MB | K 8MB | Vt 8MB | Y 8MB | Wpb 2MB   (~34MB)
  short* Q   = (short*)(ws);
  short* K   = (short*)(ws + (size_t)8388608);
  short* Vt  = (short*)(ws + (size_t)16777216);
  short* Y   = (short*)(ws + (size_t)25165824);
  short* Wpb = (short*)(ws + (size_t)33554432);
  // d_out doubles as scratch for data dead before gemm_proj writes it:
  short* Xb   = (short*)(outc);
  short* Wab  = (short*)(outc + (size_t)8388608);
  float2* tab = (float2*)(outc + (size_t)14680064);

  cvt_k<<<dim3(4096), dim3(256), 0, stream>>>(x, w_attn, w_proj, Xb, Wab, Wpb, tab);
  gemm_qkv_k<<<dim3(24, 32), dim3(256), 0, stream>>>(Xb, Wab, Q, K, Vt, tab);
  attn_k<<<dim3(B_ * H_ * (T_ / QBLK)), dim3(512), 0, stream>>>(Q, K, Vt, Y);
  gemm_proj_k<<<dim3(8, 32), dim3(256), 0, stream>>>(Y, Wpb, out);
}